// Round 6
// baseline (7721.225 us; speedup 1.0000x reference)
//
#include <hip/hip_runtime.h>
#include <math.h>

// EncoderDecoderAttentionModel: B=64, T=256, H=D=256, L=3, NSTEPS=25, C=32000
#define TT    256
#define NB    64
#define HH    256
#define NSTEP 25
#define NCLS  32000
#define PADI  3

// ---------------- static device scratch ----------------
__device__ __align__(16) float g_hring[3][2][NB][HH];   // encoder h ping-pong (coherent)
__device__ __align__(16) float g_enchid[TT][NB][HH];    // write-once (sc1 store, cached read)
__device__ __align__(16) float g_kp[NB][TT][HH];        // write-once
__device__ __align__(16) float g_vp[NB][TT][HH];        // write-once
__device__ __align__(16) float g_cfin[3][NB][HH];       // write-once
__device__ __align__(16) float g_hdec[2][3][NB][HH];    // decoder h ping-pong (coherent)
__device__ __align__(16) float g_z0[NB][512];           // [embed ; ctx] (coherent)
__device__ float    g_wmax[256][NB];                    // argmax candidates (coherent)
__device__ int      g_wmaxi[256][NB];
__device__ int      g_len[NB];
__device__ unsigned g_pa[256];                          // group-pipeline arrive flags
__device__ unsigned g_pr[4];                            // group release counters
__device__ unsigned g_ga[256];                          // global arrive flags
__device__ unsigned g_gr;                               // global release counter

__global__ void k_zero_flags(){
  g_pa[threadIdx.x] = 0u; g_ga[threadIdx.x] = 0u;
  if (threadIdx.x < 4) g_pr[threadIdx.x] = 0u;
  if (threadIdx.x == 0) g_gr = 0u;
}

__device__ __forceinline__ float sigf(float v){ return 1.0f / (1.0f + expf(-v)); }

// ---- coherent accessors (agent scope, relaxed) ----
#define SCOPE_AG __HIP_MEMORY_SCOPE_AGENT
typedef unsigned long long u64;
__device__ __forceinline__ float2 ld2(const float* p){
  u64 v = __hip_atomic_load((const u64*)p, __ATOMIC_RELAXED, SCOPE_AG);
  float2 r; __builtin_memcpy(&r, &v, 8); return r;
}
__device__ __forceinline__ float ldc(const float* p){ return __hip_atomic_load(p, __ATOMIC_RELAXED, SCOPE_AG); }
__device__ __forceinline__ void  stc(float* p, float v){ __hip_atomic_store(p, v, __ATOMIC_RELAXED, SCOPE_AG); }
__device__ __forceinline__ int   ldi(const int* p){ return __hip_atomic_load(p, __ATOMIC_RELAXED, SCOPE_AG); }
__device__ __forceinline__ void  sti(int* p, int v){ __hip_atomic_store(p, v, __ATOMIC_RELAXED, SCOPE_AG); }
__device__ __forceinline__ unsigned ldu(const unsigned* p){ return __hip_atomic_load(p, __ATOMIC_RELAXED, SCOPE_AG); }
__device__ __forceinline__ void  stu(unsigned* p, unsigned v){ __hip_atomic_store(p, v, __ATOMIC_RELAXED, SCOPE_AG); }

#define DOT4(a_, x_, w_) (a_) += (x_).x*(w_).x + (x_).y*(w_).y + (x_).z*(w_).z + (x_).w*(w_).w

// ---- per-group (64-WG) master-gather barrier ----
__device__ __forceinline__ void gbarP(int w, unsigned target){
  asm volatile("s_waitcnt vmcnt(0)" ::: "memory");
  __syncthreads();
  const int grp = w >> 6, wl = w & 63;
  if (threadIdx.x == 0) stu(&g_pa[w], target);
  if (wl == 0){
    if (threadIdx.x < 64){
      for (;;){
        unsigned a = ldu(&g_pa[(grp << 6) + threadIdx.x]);
        if (__all(a >= target)) break;
        __builtin_amdgcn_s_sleep(1);
      }
      if (threadIdx.x == 0) stu(&g_pr[grp], target);
    }
  } else if (threadIdx.x == 0){
    while (ldu(&g_pr[grp]) < target) __builtin_amdgcn_s_sleep(1);
  }
  __syncthreads();
}

// ---- global (256-WG) master-gather barrier ----
__device__ __forceinline__ void gbarG(int w, unsigned target){
  asm volatile("s_waitcnt vmcnt(0)" ::: "memory");
  __syncthreads();
  if (threadIdx.x == 0) stu(&g_ga[w], target);
  if (w == 0){
    if (threadIdx.x < 64){
      const int i4 = threadIdx.x * 4;
      for (;;){
        unsigned a0 = ldu(&g_ga[i4+0]);
        unsigned a1 = ldu(&g_ga[i4+1]);
        unsigned a2 = ldu(&g_ga[i4+2]);
        unsigned a3 = ldu(&g_ga[i4+3]);
        if (__all((a0>=target) && (a1>=target) && (a2>=target) && (a3>=target))) break;
        __builtin_amdgcn_s_sleep(1);
      }
      if (threadIdx.x == 0) stu(&g_gr, target);
    }
  } else if (threadIdx.x == 0){
    while (ldu(&g_gr) < target) __builtin_amdgcn_s_sleep(1);
  }
  __syncthreads();
}

// decoder LSTM gate GEMM (h index = WG id), K-permuted stride-36 LDS weights.
template<int NCB, int BASE>
__device__ __forceinline__ void dec_gates(const float* sw, const float* i0, const float* i1,
                                          const float* i2, int j, float out4[4]){
  float a0=0.f, a1=0.f, a2=0.f, a3=0.f;
  const float* ips[3] = { i0, i1, i2 };
  #pragma unroll
  for (int cb = 0; cb < NCB; ++cb){
    float2 xin[16];
    #pragma unroll
    for (int u = 0; u < 16; ++u) xin[u] = ld2(ips[cb] + u*16 + 2*j);
    #pragma unroll
    for (int u2 = 0; u2 < 8; ++u2){
      float2 pa = xin[2*u2], pb = xin[2*u2+1];
      const float* wb = &sw[BASE + (((cb*4+0)*8+j)*36) + u2*4];
      float4 w0 = *(const float4*)(wb);
      float4 w1 = *(const float4*)(wb + 288);
      float4 w2 = *(const float4*)(wb + 576);
      float4 w3 = *(const float4*)(wb + 864);
      a0 += pa.x*w0.x + pa.y*w0.y + pb.x*w0.z + pb.y*w0.w;
      a1 += pa.x*w1.x + pa.y*w1.y + pb.x*w1.z + pb.y*w1.w;
      a2 += pa.x*w2.x + pa.y*w2.y + pb.x*w2.z + pb.y*w2.w;
      a3 += pa.x*w3.x + pa.y*w3.y + pb.x*w3.z + pb.y*w3.w;
    }
  }
  #pragma unroll
  for (int m = 1; m < 8; m <<= 1){
    a0 += __shfl_xor(a0, m); a1 += __shfl_xor(a1, m);
    a2 += __shfl_xor(a2, m); a3 += __shfl_xor(a3, m);
  }
  out4[0]=a0; out4[1]=a1; out4[2]=a2; out4[3]=a3;
}

// LDS pool offsets (floats). Encoder: W 0..24576, stage 24576..36864,
// gat 36864..37632, c 37632..37824, hfrz 37824..38016, bias 38016..38064.
// Decoder reuses: s_w 0..8064 (stride-36), s_h2 8064..24448.
#define POOL_FL 38080

__global__ void __launch_bounds__(512, 1)
k_main(const int*   __restrict__ p_x,
       const float* __restrict__ p_eemb,
       const float* __restrict__ p_eWih,  const float* __restrict__ p_eWhh,
       const float* __restrict__ p_ebih,  const float* __restrict__ p_ebhh,
       const float* __restrict__ p_Wq, const float* __restrict__ p_bq,
       const float* __restrict__ p_Wk, const float* __restrict__ p_bk,
       const float* __restrict__ p_Wv, const float* __restrict__ p_bv,
       const float* __restrict__ p_Wo, const float* __restrict__ p_bo,
       const float* __restrict__ p_demb,
       const float* __restrict__ p_dWih0, const float* __restrict__ p_dWihR,
       const float* __restrict__ p_dWhh,
       const float* __restrict__ p_dbih,  const float* __restrict__ p_dbhh,
       const float* __restrict__ p_dW,    const float* __restrict__ p_db,
       float* __restrict__ p_out)
{
  __shared__ __align__(16) float s_pool[POOL_FL];
  __shared__ int   s_len[16];
  __shared__ __align__(16) float s_hs[256];
  __shared__ __align__(16) float s_q[256];
  __shared__ __align__(16) float s_sc[256];
  __shared__ __align__(16) float s_at[256];
  __shared__ __align__(16) float s_ctx[256];
  __shared__ float s_bdec[12];
  __shared__ float s_rv[8];  __shared__ int s_ri[8];
  __shared__ float s_rv2[8][16]; __shared__ int s_ri2[8][16];

  float* const s_W     = s_pool;              // 24576
  float* const s_stage = s_pool + 24576;      // 12288 = [3][16][256]
  float* const s_gat   = s_pool + 36864;      // 768   = [48 rows][16 lb]
  float* const s_c     = s_pool + 37632;      // 192
  float* const s_hfrz  = s_pool + 37824;      // 192
  float* const s_bias  = s_pool + 38016;      // 48

  const int w   = blockIdx.x;
  const int tid = threadIdx.x;
  unsigned barP = 0, barG = 0;

  const int grp = w >> 6, wl = w & 63;
  const int gb0 = grp << 4;                   // first global batch of the group
  // encoder thread mapping
  const int bg = tid >> 7;                    // 0..3 -> local batches 4bg..4bg+3
  const int sg = (tid >> 4) & 7;              // row group: rows {sg+8m, m<6}
  const int jk = tid & 15;                    // K lanes: k = kc*64 + 4*jk + c
  // decoder thread mapping
  const int b  = tid >> 3;
  const int j  = tid & 7;

  // ---------------- init ----------------
  // encoder weights -> LDS: row = slot_local*4 + gate; slot s = wl + 64*slot_local
  for (int fi = tid; fi < 24576; fi += 512){
    int row = fi >> 9, k = fi & 511;
    int su = row >> 2, gate = row & 3;
    int lay = su >> 2;
    int hh  = (wl + (su << 6)) & 255;
    int wrow = gate*256 + hh;
    s_W[fi] = (k < 256) ? p_eWih[((size_t)lay*1024 + wrow)*256 + k]
                        : p_eWhh[((size_t)lay*1024 + wrow)*256 + (k - 256)];
  }
  if (tid < 48){
    int su = tid >> 2, gate = tid & 3;
    int lay = su >> 2;
    int hh  = (wl + (su << 6)) & 255;
    int wrow = gate*256 + hh;
    s_bias[tid] = p_ebih[lay*1024 + wrow] + p_ebhh[lay*1024 + wrow];
  }
  if (tid < 192){ s_c[tid] = 0.f; s_hfrz[tid] = 0.f; }
  if (w < 64){                                  // lengths
    int cnt = 0;
    if (tid < 256) cnt = (p_x[w*TT + tid] != PADI) ? 1 : 0;
    #pragma unroll
    for (int m = 1; m < 64; m <<= 1) cnt += __shfl_xor(cnt, m);
    if ((tid & 63) == 0) s_ri[tid >> 6] = cnt;
    __syncthreads();
    if (tid == 0){ int t2 = 0; for (int q2 = 0; q2 < 8; ++q2) t2 += s_ri[q2]; sti(&g_len[w], t2); }
  }
  if (tid < 384){                               // zero full h-ring (both parities)
    int fi = w*384 + tid;                       // 256*384 = 98304 = 3*2*64*256
    stc(&((float*)g_hring)[fi], 0.f);
  }
  gbarG(w, ++barG);

  if (tid < 16) s_len[tid] = ldi(&g_len[gb0 + tid]);

  // ---------------- encoder: 4 independent group pipelines ----------------
  for (int d = 0; d < TT + 2; ++d){
    // stage h0[d-1], h1[d-2], h2[d-3] for the group's 16 batches (coalesced ld2)
    {
      const float* b0 = &g_hring[0][(d-1)&1][gb0][0];
      const float* b1 = &g_hring[1][ d   &1][gb0][0];
      const float* b2 = &g_hring[2][(d-1)&1][gb0][0];
      #pragma unroll
      for (int m = 0; m < 12; ++m){
        const float* src = ((m < 4) ? b0 : (m < 8) ? b1 : b2) + (m & 3)*1024 + tid*2;
        float2 v = ld2(src);
        *(float2*)&s_stage[m*1024 + tid*2] = v;
      }
    }
    __syncthreads();

    const int t0c = (d < TT) ? d : (TT - 1);
    int tok[4];
    #pragma unroll
    for (int bb = 0; bb < 4; ++bb) tok[bb] = p_x[(gb0 + bg*4 + bb)*TT + t0c];

    float acc[6][4];
    #pragma unroll
    for (int m = 0; m < 6; ++m){ acc[m][0]=0.f; acc[m][1]=0.f; acc[m][2]=0.f; acc[m][3]=0.f; }

    #pragma unroll
    for (int kc = 0; kc < 4; ++kc){
      const int ko = kc*64 + jk*4;
      float4 e4[4], h0v[4], h1v[4], h2v[4];
      #pragma unroll
      for (int bb = 0; bb < 4; ++bb){
        const int lb = bg*4 + bb;
        e4[bb]  = *(const float4*)(p_eemb + (size_t)tok[bb]*HH + ko);
        h0v[bb] = *(const float4*)&s_stage[        lb*256 + ko];
        h1v[bb] = *(const float4*)&s_stage[4096  + lb*256 + ko];
        h2v[bb] = *(const float4*)&s_stage[8192  + lb*256 + ko];
      }
      #pragma unroll
      for (int m = 0; m < 6; ++m){                 // lay = m>>1 (compile-time)
        const int row = sg + 8*m;
        float4 wx = *(const float4*)&s_W[row*512 + ko];
        float4 wh = *(const float4*)&s_W[row*512 + 256 + ko];
        #pragma unroll
        for (int bb = 0; bb < 4; ++bb){
          float4 xs = (m < 2) ? e4[bb]  : (m < 4) ? h0v[bb] : h1v[bb];
          float4 hs = (m < 2) ? h0v[bb] : (m < 4) ? h1v[bb] : h2v[bb];
          acc[m][bb] += xs.x*wx.x + xs.y*wx.y + xs.z*wx.z + xs.w*wx.w
                      + hs.x*wh.x + hs.y*wh.y + hs.z*wh.z + hs.w*wh.w;
        }
      }
    }

    // reduce over the 16 jk lanes
    #pragma unroll
    for (int m = 0; m < 6; ++m){
      #pragma unroll
      for (int bb = 0; bb < 4; ++bb){
        float v = acc[m][bb];
        v += __shfl_xor(v, 1); v += __shfl_xor(v, 2);
        v += __shfl_xor(v, 4); v += __shfl_xor(v, 8);
        acc[m][bb] = v;
      }
    }
    if (jk == 0){
      #pragma unroll
      for (int m = 0; m < 6; ++m){
        #pragma unroll
        for (int bb = 0; bb < 4; ++bb)
          s_gat[(sg + 8*m)*16 + bg*4 + bb] = acc[m][bb];
      }
    }
    __syncthreads();

    if (tid < 192){                               // cell update: (slot su, local batch lb)
      const int su = tid >> 4, lb = tid & 15;
      const int lay = su >> 2;
      const int hh  = (wl + (su << 6)) & 255;
      const int t = d - lay;
      if (t >= 0 && t < TT){
        float iv = s_gat[(su*4+0)*16 + lb] + s_bias[su*4+0];
        float fv = s_gat[(su*4+1)*16 + lb] + s_bias[su*4+1];
        float gv = s_gat[(su*4+2)*16 + lb] + s_bias[su*4+2];
        float ov = s_gat[(su*4+3)*16 + lb] + s_bias[su*4+3];
        float cc = s_c[tid], hp = s_hfrz[tid];
        float c2 = sigf(fv)*cc + sigf(iv)*tanhf(gv);
        float h2x = sigf(ov)*tanhf(c2);
        bool valid = (t < s_len[lb]);
        float ho = valid ? h2x : hp;
        if (valid) s_c[tid] = c2;
        s_hfrz[tid] = ho;
        stc(&g_hring[lay][t & 1][gb0 + lb][hh], ho);
        if (lay == 2) stc(&g_enchid[t][gb0 + lb][hh], valid ? ho : 0.f);
      }
    }
    gbarP(w, ++barP);
  }

  if (tid < 192){                                 // final c -> global
    const int su = tid >> 4, lb = tid & 15;
    const int lay = su >> 2;
    const int hh  = (wl + (su << 6)) & 255;
    stc(&g_cfin[lay][gb0 + lb][hh], s_c[tid]);
  }
  gbarG(w, ++barG);                               // join the 4 pipelines

  // ------- K/V projections (enchid: first-ever cached reads) -------
  {
    const int b3 = w >> 2, t0 = (w & 3) * 64;
    const int n1 = tid & 127, rq = tid >> 7;
    for (int p = 0; p < 4; ++p){
      const int n = p*128 + n1;
      const float* wrow = (n < 256) ? (p_Wk + (size_t)n*HH) : (p_Wv + (size_t)(n-256)*HH);
      const float bias  = (n < 256) ? p_bk[n] : p_bv[n-256];
      const float4* wr4 = (const float4*)wrow;
      const float* hb = &g_enchid[t0 + rq*16][b3][0];
      const float4* hr[16];
      #pragma unroll
      for (int r = 0; r < 16; ++r) hr[r] = (const float4*)(hb + (size_t)r*NB*HH);
      float a16[16];
      #pragma unroll
      for (int r = 0; r < 16; ++r) a16[r] = 0.f;
      for (int k4 = 0; k4 < 64; ++k4){
        float4 wv = wr4[k4];
        #pragma unroll
        for (int r = 0; r < 16; ++r){ float4 h4 = hr[r][k4]; DOT4(a16[r], h4, wv); }
      }
      float* orow = (n < 256) ? &g_kp[b3][t0 + rq*16][n] : &g_vp[b3][t0 + rq*16][n-256];
      #pragma unroll
      for (int r = 0; r < 16; ++r) stc(orow + (size_t)r*HH, a16[r] + bias);
    }
  }

  // decoder weights for h=w (all 3 layers) -> pool[0..8064), stride-36 K-permuted
  {
    float* s_w = s_pool;
    for (int fi = tid; fi < 3072; fi += 512){
      int g = fi / 768, k = fi % 768; int row = g*256 + w;
      float v = (k < 512) ? p_dWih0[(size_t)row*512 + k]
                          : p_dWhh[(size_t)row*HH + (k - 512)];
      int cb = k >> 8, kk = k & 255;
      s_w[(((cb*4 + g)*8 + ((kk & 15) >> 1))*36) + (((kk >> 4) << 1) | (kk & 1))] = v;
    }
    for (int fi = tid; fi < 2048; fi += 512){
      int g = fi / 512, k = fi % 512; int row = g*256 + w;
      float v = (k < 256) ? p_dWihR[(size_t)row*HH + k]
                          : p_dWhh[(size_t)(1024 + row)*HH + (k - 256)];
      int cb = k >> 8, kk = k & 255;
      s_w[3456 + (((cb*4 + g)*8 + ((kk & 15) >> 1))*36) + (((kk >> 4) << 1) | (kk & 1))] = v;
    }
    for (int fi = tid; fi < 2048; fi += 512){
      int g = fi / 512, k = fi % 512; int row = g*256 + w;
      float v = (k < 256) ? p_dWihR[(size_t)(1024 + row)*HH + k]
                          : p_dWhh[(size_t)(2048 + row)*HH + (k - 256)];
      int cb = k >> 8, kk = k & 255;
      s_w[5760 + (((cb*4 + g)*8 + ((kk & 15) >> 1))*36) + (((kk >> 4) << 1) | (kk & 1))] = v;
    }
    if (tid < 12){
      int l = tid >> 2, g = tid & 3; int row = g*256 + w;
      s_bdec[tid] = p_dbih[l*1024 + row] + p_dbhh[l*1024 + row];
    }
  }
  gbarG(w, ++barG);

  // ---------------- decoder init ----------------
  if (tid < 192){
    int fi = w*192 + tid;
    int l = fi >> 14, rem = fi & 16383;
    stc(&g_hdec[0][l][rem >> 8][rem & 255], ldc(&g_hring[l][1][rem >> 8][rem & 255]));
  }
  float c_d0 = 0.f, c_d1 = 0.f, c_d2 = 0.f;
  if (j == 0){
    c_d0 = ldc(&g_cfin[0][b][w]); c_d1 = ldc(&g_cfin[1][b][w]); c_d2 = ldc(&g_cfin[2][b][w]);
  }
  gbarG(w, ++barG);

  float* const s_w  = s_pool;
  float* const s_h2 = s_pool + 8064;

  // ---------------- decoder steps ----------------
  for (int st = 0; st < NSTEP; ++st){
    const int slot = st & 1, nxt = slot ^ 1;

    // ---- stage A: argmax-reduce, embed, attention, z0 (WGs 0..63) ----
    if (w < 64){
      const int bA = w;
      int tok = 0;                                  // SOS
      if (st > 0){
        float v = -1e38f; int idx = 0;
        if (tid < 256){ v = ldc(&g_wmax[tid][bA]); idx = ldi(&g_wmaxi[tid][bA]); }
        #pragma unroll
        for (int m = 1; m < 64; m <<= 1){
          float ov = __shfl_xor(v, m); int oi = __shfl_xor(idx, m);
          if (ov > v || (ov == v && oi < idx)){ v = ov; idx = oi; }
        }
        if ((tid & 63) == 0){ s_rv[tid >> 6] = v; s_ri[tid >> 6] = idx; }
        __syncthreads();
        if (tid == 0){
          float bv2 = s_rv[0]; int bi2 = s_ri[0];
          for (int q2 = 1; q2 < 8; ++q2){
            float ov = s_rv[q2]; int oi = s_ri[q2];
            if (ov > bv2 || (ov == bv2 && oi < bi2)){ bv2 = ov; bi2 = oi; }
          }
          s_ri[0] = bi2;
        }
        __syncthreads();
        tok = s_ri[0];
      }
      if (tid < 256)
        s_hs[tid] = ldc(&g_hdec[slot][0][bA][tid]) + ldc(&g_hdec[slot][1][bA][tid])
                  + ldc(&g_hdec[slot][2][bA][tid]);
      __syncthreads();
      if (tid < 256){                                // q = hsum @ Wq.T + bq
        float a = p_bq[tid];
        const float4* wr = (const float4*)(p_Wq + (size_t)tid*HH);
        #pragma unroll 8
        for (int k4 = 0; k4 < 64; ++k4){
          float4 wv = wr[k4]; float4 h4 = *(const float4*)&s_hs[k4*4]; DOT4(a, h4, wv);
        }
        s_q[tid] = a;
      }
      __syncthreads();
      if (tid < 256){                                // scores
        float a = 0.f;
        const float4* kr = (const float4*)&g_kp[bA][tid][0];
        #pragma unroll 8
        for (int k4 = 0; k4 < 64; ++k4){
          float4 kv = kr[k4]; float4 q4 = *(const float4*)&s_q[k4*4]; DOT4(a, q4, kv);
        }
        s_sc[tid] = a * 0.0625f;                     // 1/sqrt(256)
      }
      __syncthreads();
      {                                              // softmax
        float sv = (tid < 256) ? s_sc[tid] : -1e38f;
        float m2 = sv;
        #pragma unroll
        for (int m = 1; m < 64; m <<= 1) m2 = fmaxf(m2, __shfl_xor(m2, m));
        if ((tid & 63) == 0) s_rv[tid >> 6] = m2;
        __syncthreads();
        if (tid == 0){ float mm = s_rv[0]; for (int q2 = 1; q2 < 8; ++q2) mm = fmaxf(mm, s_rv[q2]); s_rv[0] = mm; }
        __syncthreads();
        const float mx = s_rv[0];
        float ev = (tid < 256) ? expf(sv - mx) : 0.f;
        float ss = ev;
        #pragma unroll
        for (int m = 1; m < 64; m <<= 1) ss += __shfl_xor(ss, m);
        __syncthreads();
        if ((tid & 63) == 0) s_rv[tid >> 6] = ss;
        __syncthreads();
        if (tid == 0){ float t2 = 0.f; for (int q2 = 0; q2 < 8; ++q2) t2 += s_rv[q2]; s_rv[0] = t2; }
        __syncthreads();
        if (tid < 256) s_at[tid] = ev / s_rv[0];
      }
      __syncthreads();
      if (tid < 256){                                // ctx = attn @ vp
        float a = 0.f;
        const float* vb = &g_vp[bA][0][tid];
        #pragma unroll 4
        for (int t4 = 0; t4 < 64; ++t4){
          float4 a4 = *(const float4*)&s_at[t4*4];
          a += a4.x*vb[(size_t)(t4*4+0)*HH] + a4.y*vb[(size_t)(t4*4+1)*HH]
             + a4.z*vb[(size_t)(t4*4+2)*HH] + a4.w*vb[(size_t)(t4*4+3)*HH];
        }
        s_ctx[tid] = a;
      }
      __syncthreads();
      if (tid < 256){                                // ctx @ Wo.T + bo ; z0
        float a = p_bo[tid];
        const float4* wr = (const float4*)(p_Wo + (size_t)tid*HH);
        #pragma unroll 8
        for (int k4 = 0; k4 < 64; ++k4){
          float4 wv = wr[k4]; float4 c4 = *(const float4*)&s_ctx[k4*4]; DOT4(a, c4, wv);
        }
        stc(&g_z0[bA][256 + tid], a);
        stc(&g_z0[bA][tid], p_demb[(size_t)tok*HH + tid]);
      }
    }
    gbarG(w, ++barG);

    // ---- stages B/C/D: 3 LSTM layers, h=w per WG ----
    {
      float g4[4];
      dec_gates<3, 0>(s_w, &g_z0[b][0], &g_z0[b][256], &g_hdec[slot][0][b][0], j, g4);
      if (j == 0){
        float iv = g4[0]+s_bdec[0], fv = g4[1]+s_bdec[1], gv = g4[2]+s_bdec[2], ov = g4[3]+s_bdec[3];
        float c2 = sigf(fv)*c_d0 + sigf(iv)*tanhf(gv); c_d0 = c2;
        stc(&g_hdec[nxt][0][b][w], sigf(ov)*tanhf(c2));
      }
    }
    gbarG(w, ++barG);
    {
      float g4[4];
      dec_gates<2, 3456>(s_w, &g_hdec[nxt][0][b][0], &g_hdec[slot][1][b][0], nullptr, j, g4);
      if (j == 0){
        float iv = g4[0]+s_bdec[4], fv = g4[1]+s_bdec[5], gv = g4[2]+s_bdec[6], ov = g4[3]+s_bdec[7];
        float c2 = sigf(fv)*c_d1 + sigf(iv)*tanhf(gv); c_d1 = c2;
        stc(&g_hdec[nxt][1][b][w], sigf(ov)*tanhf(c2));
      }
    }
    gbarG(w, ++barG);
    {
      float g4[4];
      dec_gates<2, 5760>(s_w, &g_hdec[nxt][1][b][0], &g_hdec[slot][2][b][0], nullptr, j, g4);
      if (j == 0){
        float iv = g4[0]+s_bdec[8], fv = g4[1]+s_bdec[9], gv = g4[2]+s_bdec[10], ov = g4[3]+s_bdec[11];
        float c2 = sigf(fv)*c_d2 + sigf(iv)*tanhf(gv); c_d2 = c2;
        stc(&g_hdec[nxt][2][b][w], sigf(ov)*tanhf(c2));
      }
    }
    gbarG(w, ++barG);

    // ---- stage E: logits GEMM (125 classes/WG) + partial argmax ----
    {
      {  // coalesced coherent staging of h2 (64x256) into LDS
        const float* src = &g_hdec[nxt][2][0][0];
        #pragma unroll
        for (int u = 0; u < 16; ++u){
          int fo = 2*(tid + 512*u);
          float2 v = ld2(src + fo);
          *(float2*)(s_h2 + fo) = v;
        }
      }
      __syncthreads();

      const int cq = tid & 127, qb = tid >> 7;
      const bool cok = (cq < 125);
      const int c  = w*125 + cq;
      const int cc = cok ? c : (w*125);
      const float4* wr = (const float4*)(p_dW + (size_t)cc*HH);
      const float4* zr[16];
      #pragma unroll
      for (int r = 0; r < 16; ++r) zr[r] = (const float4*)&s_h2[(qb*16 + r)*HH];
      float a16[16];
      #pragma unroll
      for (int r = 0; r < 16; ++r) a16[r] = 0.f;
      for (int k4 = 0; k4 < 64; ++k4){
        float4 wv = wr[k4];
        #pragma unroll
        for (int r = 0; r < 16; ++r){ float4 z4 = zr[r][k4]; DOT4(a16[r], z4, wv); }
      }
      const float bias = cok ? p_db[cc] : 0.f;
      #pragma unroll
      for (int r = 0; r < 16; ++r){
        const int bb = qb*16 + r;
        float val = a16[r] + bias;
        if (cok) p_out[((size_t)bb*NSTEP + st)*NCLS + c] = val;
        float v = cok ? val : -1e38f;
        int idx = cok ? c : 0x7fffffff;
        #pragma unroll
        for (int m = 1; m < 64; m <<= 1){
          float ov = __shfl_xor(v, m); int oi = __shfl_xor(idx, m);
          if (ov > v || (ov == v && oi < idx)){ v = ov; idx = oi; }  // first-index tie-break
        }
        if ((tid & 63) == 0){ s_rv2[tid >> 6][r] = v; s_ri2[tid >> 6][r] = idx; }
      }
      __syncthreads();
      if (tid < 64){
        const int qb2 = tid >> 4, r = tid & 15;
        float v1 = s_rv2[qb2*2][r];   int i1 = s_ri2[qb2*2][r];
        float v2 = s_rv2[qb2*2+1][r]; int i2 = s_ri2[qb2*2+1][r];
        bool take2 = (v2 > v1) || (v2 == v1 && i2 < i1);
        stc(&g_wmax[w][qb2*16 + r],  take2 ? v2 : v1);
        sti(&g_wmaxi[w][qb2*16 + r], take2 ? i2 : i1);
      }
      __syncthreads();
    }
    gbarG(w, ++barG);
  }
}

extern "C" void kernel_launch(void* const* d_in, const int* in_sizes, int n_in,
                              void* d_out, int out_size, void* d_ws, size_t ws_size,
                              hipStream_t stream){
  (void)in_sizes; (void)n_in; (void)out_size; (void)d_ws; (void)ws_size;
  const int*   x     = (const int*)d_in[0];
  const float* eemb  = (const float*)d_in[2];
  const float* eWih  = (const float*)d_in[3];
  const float* eWhh  = (const float*)d_in[4];
  const float* ebih  = (const float*)d_in[5];
  const float* ebhh  = (const float*)d_in[6];
  const float* Wq    = (const float*)d_in[7];
  const float* bq    = (const float*)d_in[8];
  const float* Wk    = (const float*)d_in[9];
  const float* bk    = (const float*)d_in[10];
  const float* Wv    = (const float*)d_in[11];
  const float* bv    = (const float*)d_in[12];
  const float* Wo    = (const float*)d_in[13];
  const float* bo    = (const float*)d_in[14];
  const float* demb  = (const float*)d_in[15];
  const float* dWih0 = (const float*)d_in[16];
  const float* dWihR = (const float*)d_in[17];
  const float* dWhh  = (const float*)d_in[18];
  const float* dbih  = (const float*)d_in[19];
  const float* dbhh  = (const float*)d_in[20];
  const float* dW    = (const float*)d_in[21];
  const float* db    = (const float*)d_in[22];
  float* out = (float*)d_out;

  k_zero_flags<<<dim3(1), dim3(256), 0, stream>>>();
  k_main<<<dim3(256), dim3(512), 0, stream>>>(
      x, eemb, eWih, eWhh, ebih, ebhh,
      Wq, bq, Wk, bk, Wv, bv, Wo, bo,
      demb, dWih0, dWihR, dWhh, dbih, dbhh, dW, db, out);
}

// Round 7
// 5863.337 us; speedup vs baseline: 1.3169x; 1.3169x over previous
//
#include <hip/hip_runtime.h>
#include <math.h>

// EncoderDecoderAttentionModel: B=64, T=256, H=D=256, L=3, NSTEPS=25, C=32000
#define TT    256
#define NB    64
#define HH    256
#define NSTEP 25
#define NCLS  32000
#define PADI  3

// ---------------- static device scratch ----------------
__device__ __align__(16) float g_hring[3][2][NB][HH];   // encoder h ping-pong (coherent)
__device__ __align__(16) float g_enchid[TT][NB][HH];    // write-once
__device__ __align__(16) float g_kp[NB][TT][HH];        // write-once
__device__ __align__(16) float g_vp[NB][TT][HH];        // write-once
__device__ __align__(16) float g_cfin[3][NB][HH];       // write-once
__device__ __align__(16) float g_hdec[2][3][NB][HH];    // decoder h ping-pong (coherent)
__device__ __align__(16) float g_z0[NB][512];           // [embed ; ctx] (coherent)
__device__ float    g_wmax[256][NB];                    // argmax candidates (coherent)
__device__ int      g_wmaxi[256][NB];
__device__ int      g_len[NB];
__device__ unsigned g_arrive[256];                      // barrier arrive flags
__device__ unsigned g_rel[256];                         // 16 release lines, stride 16 u32 (64B)

__global__ void k_zero_flags(){
  g_arrive[threadIdx.x] = 0u;
  g_rel[threadIdx.x] = 0u;
}

__device__ __forceinline__ float sigf(float v){ return 1.0f / (1.0f + expf(-v)); }

// ---- coherent accessors (agent scope, relaxed): visible chip-wide w/o fences ----
#define SCOPE_AG __HIP_MEMORY_SCOPE_AGENT
typedef unsigned long long u64;
__device__ __forceinline__ float2 ld2(const float* p){
  u64 v = __hip_atomic_load((const u64*)p, __ATOMIC_RELAXED, SCOPE_AG);
  float2 r; __builtin_memcpy(&r, &v, 8); return r;
}
__device__ __forceinline__ float ldc(const float* p){ return __hip_atomic_load(p, __ATOMIC_RELAXED, SCOPE_AG); }
__device__ __forceinline__ void  stc(float* p, float v){ __hip_atomic_store(p, v, __ATOMIC_RELAXED, SCOPE_AG); }
__device__ __forceinline__ int   ldi(const int* p){ return __hip_atomic_load(p, __ATOMIC_RELAXED, SCOPE_AG); }
__device__ __forceinline__ void  sti(int* p, int v){ __hip_atomic_store(p, v, __ATOMIC_RELAXED, SCOPE_AG); }
__device__ __forceinline__ unsigned ldu(const unsigned* p){ return __hip_atomic_load(p, __ATOMIC_RELAXED, SCOPE_AG); }
__device__ __forceinline__ void  stu(unsigned* p, unsigned v){ __hip_atomic_store(p, v, __ATOMIC_RELAXED, SCOPE_AG); }

#define DOT4(a_, x_, w_) (a_) += (x_).x*(w_).x + (x_).y*(w_).y + (x_).z*(w_).z + (x_).w*(w_).w

// LDS weight layout: [cb][gate][j][36] with K-permutation k = 16u + 2j + c
#define WENC(cb,g,jj,u) (((((cb)*12+(g))*8+(jj))*36)+(u))

// ---- two-level master-gather barrier with FAN-OUT release (16 padded lines) ----
// Arrive: 256 distinct-address stores. Gather: WG 0 polls all 256.
// Release: master stores to 16 lines (64B apart); WG w polls line w>>4
// -> only 16 pollers per line, no LLC same-line queueing.
__device__ __forceinline__ void gbar(int w, unsigned target){
  asm volatile("s_waitcnt vmcnt(0)" ::: "memory");
  __syncthreads();
  if (threadIdx.x == 0) stu(&g_arrive[w], target);
  if (w == 0){
    if (threadIdx.x < 64){
      const int i4 = threadIdx.x * 4;
      for (;;){
        unsigned a0 = ldu(&g_arrive[i4+0]);
        unsigned a1 = ldu(&g_arrive[i4+1]);
        unsigned a2 = ldu(&g_arrive[i4+2]);
        unsigned a3 = ldu(&g_arrive[i4+3]);
        if (__all((a0>=target) && (a1>=target) && (a2>=target) && (a3>=target))) break;
        __builtin_amdgcn_s_sleep(1);
      }
      if (threadIdx.x < 16) stu(&g_rel[threadIdx.x << 4], target);
    }
  } else {
    if (threadIdx.x == 0){
      const unsigned* line = &g_rel[(w >> 4) << 4];
      while (ldu(line) < target) __builtin_amdgcn_s_sleep(1);
    }
  }
  __syncthreads();
}

// decoder LSTM gate GEMM: 4 gate rows (h index = WG id), inputs coherent+coalesced.
template<int NCB, int BASE>
__device__ __forceinline__ void dec_gates(const float* sw, const float* i0, const float* i1,
                                          const float* i2, int j, float out4[4]){
  float a0=0.f, a1=0.f, a2=0.f, a3=0.f;
  const float* ips[3] = { i0, i1, i2 };
  #pragma unroll
  for (int cb = 0; cb < NCB; ++cb){
    float2 xin[16];
    #pragma unroll
    for (int u = 0; u < 16; ++u) xin[u] = ld2(ips[cb] + u*16 + 2*j);
    #pragma unroll
    for (int u2 = 0; u2 < 8; ++u2){
      float2 pa = xin[2*u2], pb = xin[2*u2+1];
      const float* wb = &sw[BASE + (((cb*4+0)*8+j)*36) + u2*4];
      float4 w0 = *(const float4*)(wb);
      float4 w1 = *(const float4*)(wb + 288);
      float4 w2 = *(const float4*)(wb + 576);
      float4 w3 = *(const float4*)(wb + 864);
      a0 += pa.x*w0.x + pa.y*w0.y + pb.x*w0.z + pb.y*w0.w;
      a1 += pa.x*w1.x + pa.y*w1.y + pb.x*w1.z + pb.y*w1.w;
      a2 += pa.x*w2.x + pa.y*w2.y + pb.x*w2.z + pb.y*w2.w;
      a3 += pa.x*w3.x + pa.y*w3.y + pb.x*w3.z + pb.y*w3.w;
    }
  }
  #pragma unroll
  for (int m = 1; m < 8; m <<= 1){
    a0 += __shfl_xor(a0, m); a1 += __shfl_xor(a1, m);
    a2 += __shfl_xor(a2, m); a3 += __shfl_xor(a3, m);
  }
  out4[0]=a0; out4[1]=a1; out4[2]=a2; out4[3]=a3;
}

__global__ void __launch_bounds__(512, 1)
k_main(const int*   __restrict__ p_x,
       const float* __restrict__ p_eemb,
       const float* __restrict__ p_eWih,  const float* __restrict__ p_eWhh,
       const float* __restrict__ p_ebih,  const float* __restrict__ p_ebhh,
       const float* __restrict__ p_Wq, const float* __restrict__ p_bq,
       const float* __restrict__ p_Wk, const float* __restrict__ p_bk,
       const float* __restrict__ p_Wv, const float* __restrict__ p_bv,
       const float* __restrict__ p_Wo, const float* __restrict__ p_bo,
       const float* __restrict__ p_demb,
       const float* __restrict__ p_dWih0, const float* __restrict__ p_dWihR,
       const float* __restrict__ p_dWhh,
       const float* __restrict__ p_dbih,  const float* __restrict__ p_dbhh,
       const float* __restrict__ p_dW,    const float* __restrict__ p_db,
       float* __restrict__ p_out)
{
  __shared__ __align__(16) float s_w[8064];       // enc: 6912 used; dec: 8064 used
  __shared__ __align__(16) float s_h2[NB*HH];     // stage-E h2 staging, flat [64][256]
  __shared__ float s_benc[12];
  __shared__ float s_bdec[12];
  __shared__ __align__(16) float s_hs[256];
  __shared__ __align__(16) float s_q[256];
  __shared__ __align__(16) float s_sc[256];
  __shared__ __align__(16) float s_at[256];
  __shared__ __align__(16) float s_ctx[256];
  __shared__ float s_rv[8];  __shared__ int s_ri[8];

  const int w   = blockIdx.x;
  const int tid = threadIdx.x;
  const int b   = tid >> 3;      // batch lane (0..63)
  const int j   = tid & 7;       // K-split lane (0..7); owns k = {16u + 2j + c}
  unsigned bar  = 0;

  const int lay0 = (w < 255) ? (w / 85) : 0;
  const int h0   = (w < 255) ? ((w - lay0*85) * 3) : 0;

  // ---------------- init: lengths, encoder weights -> LDS (permuted), zero ring ----
  for (int fi = tid; fi < 6144; fi += 512){
    int g = fi >> 9, k = fi & 511;
    int e = g >> 2, gt = g & 3;
    int l   = (w < 255) ? lay0 : e;
    int hh2 = (w < 255) ? (h0 + e) : 255;
    int row = gt*256 + hh2;
    float v = (k < 256) ? p_eWih[((size_t)l*1024 + row)*256 + k]
                        : p_eWhh[((size_t)l*1024 + row)*256 + (k - 256)];
    int cb = k >> 8, kk = k & 255;
    s_w[WENC(cb, g, (kk & 15) >> 1, ((kk >> 4) << 1) | (kk & 1))] = v;
  }
  if (tid < 12){
    int e = tid >> 2, gt = tid & 3;
    int l   = (w < 255) ? lay0 : e;
    int hh2 = (w < 255) ? (h0 + e) : 255;
    int row = gt*256 + hh2;
    s_benc[tid] = p_ebih[l*1024 + row] + p_ebhh[l*1024 + row];
  }
  if (w < 64){
    int cnt = 0;
    if (tid < 256) cnt = (p_x[w*TT + tid] != PADI) ? 1 : 0;
    #pragma unroll
    for (int m = 1; m < 64; m <<= 1) cnt += __shfl_xor(cnt, m);
    if ((tid & 63) == 0) s_ri[tid >> 6] = cnt;
    __syncthreads();
    if (tid == 0){ int t2 = 0; for (int q2 = 0; q2 < 8; ++q2) t2 += s_ri[q2]; sti(&g_len[w], t2); }
  }
  if (tid < 192){                       // zero initial-state slot (slot 1 == "t=-1")
    int fi = w*192 + tid;
    int l = fi >> 14, rem = fi & 16383;
    stc(&g_hring[l][1][rem >> 8][rem & 255], 0.f);
  }
  gbar(w, ++bar);

  const int len_b = ldi(&g_len[b]);

  // ---------------- encoder: layer-wavefront over diagonals ----------------
  float c_reg[3] = {0.f,0.f,0.f};
  float h_reg[3] = {0.f,0.f,0.f};

  for (int sdiag = 0; sdiag < TT + 2; ++sdiag){
    float acc[12];
    #pragma unroll
    for (int g = 0; g < 12; ++g) acc[g] = 0.f;

    if (w < 255){
      const int t = sdiag - lay0;
      if (t >= 0 && t < TT){
        float2 x2[16], h2[16];
        if (lay0 == 0){
          const float* xs = p_eemb + (size_t)p_x[b*TT + t]*HH;
          #pragma unroll
          for (int u = 0; u < 16; ++u) x2[u] = *(const float2*)(xs + u*16 + 2*j);
        } else {
          const float* xs = &g_hring[lay0-1][t & 1][b][0];
          #pragma unroll
          for (int u = 0; u < 16; ++u) x2[u] = ld2(xs + u*16 + 2*j);
        }
        {
          const float* hsv = &g_hring[lay0][(t & 1) ^ 1][b][0];
          #pragma unroll
          for (int u = 0; u < 16; ++u) h2[u] = ld2(hsv + u*16 + 2*j);
        }
        #pragma unroll
        for (int u2 = 0; u2 < 8; ++u2){
          float2 xa = x2[2*u2], xb = x2[2*u2+1];
          float2 ha = h2[2*u2], hb = h2[2*u2+1];
          #pragma unroll
          for (int g = 0; g < 12; ++g){
            float4 wx = *(const float4*)&s_w[WENC(0, g, j, u2*4)];
            float4 wh = *(const float4*)&s_w[WENC(1, g, j, u2*4)];
            acc[g] += xa.x*wx.x + xa.y*wx.y + xb.x*wx.z + xb.y*wx.w
                    + ha.x*wh.x + ha.y*wh.y + hb.x*wh.z + hb.y*wh.w;
          }
        }
      }
    } else {
      #pragma unroll
      for (int e = 0; e < 3; ++e){
        const int t = sdiag - e;
        if (t >= 0 && t < TT){
          float2 x2[16], h2[16];
          if (e == 0){
            const float* xs = p_eemb + (size_t)p_x[b*TT + t]*HH;
            #pragma unroll
            for (int u = 0; u < 16; ++u) x2[u] = *(const float2*)(xs + u*16 + 2*j);
          } else {
            const float* xs = &g_hring[e-1][t & 1][b][0];
            #pragma unroll
            for (int u = 0; u < 16; ++u) x2[u] = ld2(xs + u*16 + 2*j);
          }
          {
            const float* hsv = &g_hring[e][(t & 1) ^ 1][b][0];
            #pragma unroll
            for (int u = 0; u < 16; ++u) h2[u] = ld2(hsv + u*16 + 2*j);
          }
          #pragma unroll
          for (int u2 = 0; u2 < 8; ++u2){
            float2 xa = x2[2*u2], xb = x2[2*u2+1];
            float2 ha = h2[2*u2], hb = h2[2*u2+1];
            #pragma unroll
            for (int g2 = 0; g2 < 4; ++g2){
              float4 wx = *(const float4*)&s_w[WENC(0, e*4+g2, j, u2*4)];
              float4 wh = *(const float4*)&s_w[WENC(1, e*4+g2, j, u2*4)];
              acc[e*4+g2] += xa.x*wx.x + xa.y*wx.y + xb.x*wx.z + xb.y*wx.w
                           + ha.x*wh.x + ha.y*wh.y + hb.x*wh.z + hb.y*wh.w;
            }
          }
        }
      }
    }

    #pragma unroll
    for (int g = 0; g < 12; ++g){
      float v = acc[g];
      v += __shfl_xor(v, 1); v += __shfl_xor(v, 2); v += __shfl_xor(v, 4);
      acc[g] = v;
    }

    if (j == 0){
      #pragma unroll
      for (int e = 0; e < 3; ++e){
        const int lay = (w < 255) ? lay0 : e;
        const int hh2 = (w < 255) ? (h0 + e) : 255;
        const int t = sdiag - lay;
        if (t >= 0 && t < TT){
          float iv = acc[e*4+0] + s_benc[e*4+0];
          float fv = acc[e*4+1] + s_benc[e*4+1];
          float gv = acc[e*4+2] + s_benc[e*4+2];
          float ov = acc[e*4+3] + s_benc[e*4+3];
          float c2 = sigf(fv)*c_reg[e] + sigf(iv)*tanhf(gv);
          float h2v = sigf(ov)*tanhf(c2);
          bool valid = (t < len_b);
          if (valid){ c_reg[e] = c2; h_reg[e] = h2v; }   // freeze past length
          stc(&g_hring[lay][t & 1][b][hh2], h_reg[e]);
          if (lay == 2) stc(&g_enchid[t][b][hh2], valid ? h_reg[e] : 0.f);
        }
      }
    }
    gbar(w, ++bar);
  }

  if (j == 0){
    #pragma unroll
    for (int e = 0; e < 3; ++e){
      const int lay = (w < 255) ? lay0 : e;
      const int hh2 = (w < 255) ? (h0 + e) : 255;
      stc(&g_cfin[lay][b][hh2], c_reg[e]);
    }
  }
  gbar(w, ++bar);

  // ------- K/V projections -------
  {
    const int b3 = w >> 2, t0 = (w & 3) * 64;
    const int n1 = tid & 127, rq = tid >> 7;
    for (int p = 0; p < 4; ++p){
      const int n = p*128 + n1;
      const float* wrow = (n < 256) ? (p_Wk + (size_t)n*HH) : (p_Wv + (size_t)(n-256)*HH);
      const float bias  = (n < 256) ? p_bk[n] : p_bv[n-256];
      const float4* wr4 = (const float4*)wrow;
      const float* hb = &g_enchid[t0 + rq*16][b3][0];
      const float4* hr[16];
      #pragma unroll
      for (int r = 0; r < 16; ++r) hr[r] = (const float4*)(hb + (size_t)r*NB*HH);
      float a16[16];
      #pragma unroll
      for (int r = 0; r < 16; ++r) a16[r] = 0.f;
      for (int k4 = 0; k4 < 64; ++k4){
        float4 wv = wr4[k4];
        #pragma unroll
        for (int r = 0; r < 16; ++r){ float4 h4 = hr[r][k4]; DOT4(a16[r], h4, wv); }
      }
      float* orow = (n < 256) ? &g_kp[b3][t0 + rq*16][n] : &g_vp[b3][t0 + rq*16][n-256];
      #pragma unroll
      for (int r = 0; r < 16; ++r) stc(orow + (size_t)r*HH, a16[r] + bias);
    }
  }

  // decoder weights for h=w (all 3 layers) -> LDS, K-permuted stride-36
  for (int fi = tid; fi < 3072; fi += 512){
    int g = fi / 768, k = fi % 768; int row = g*256 + w;
    float v = (k < 512) ? p_dWih0[(size_t)row*512 + k]
                        : p_dWhh[(size_t)row*HH + (k - 512)];
    int cb = k >> 8, kk = k & 255;
    s_w[(((cb*4 + g)*8 + ((kk & 15) >> 1))*36) + (((kk >> 4) << 1) | (kk & 1))] = v;
  }
  for (int fi = tid; fi < 2048; fi += 512){
    int g = fi / 512, k = fi % 512; int row = g*256 + w;
    float v = (k < 256) ? p_dWihR[(size_t)row*HH + k]
                        : p_dWhh[(size_t)(1024 + row)*HH + (k - 256)];
    int cb = k >> 8, kk = k & 255;
    s_w[3456 + (((cb*4 + g)*8 + ((kk & 15) >> 1))*36) + (((kk >> 4) << 1) | (kk & 1))] = v;
  }
  for (int fi = tid; fi < 2048; fi += 512){
    int g = fi / 512, k = fi % 512; int row = g*256 + w;
    float v = (k < 256) ? p_dWihR[(size_t)(1024 + row)*HH + k]
                        : p_dWhh[(size_t)(2048 + row)*HH + (k - 256)];
    int cb = k >> 8, kk = k & 255;
    s_w[5760 + (((cb*4 + g)*8 + ((kk & 15) >> 1))*36) + (((kk >> 4) << 1) | (kk & 1))] = v;
  }
  if (tid < 12){
    int l = tid >> 2, g = tid & 3; int row = g*256 + w;
    s_bdec[tid] = p_dbih[l*1024 + row] + p_dbhh[l*1024 + row];
  }
  gbar(w, ++bar);

  // ---------------- decoder init ----------------
  if (tid < 192){
    int fi = w*192 + tid;
    int l = fi >> 14, rem = fi & 16383;
    stc(&g_hdec[0][l][rem >> 8][rem & 255], ldc(&g_hring[l][1][rem >> 8][rem & 255]));
  }
  float c_d0 = 0.f, c_d1 = 0.f, c_d2 = 0.f;
  if (j == 0){
    c_d0 = ldc(&g_cfin[0][b][w]); c_d1 = ldc(&g_cfin[1][b][w]); c_d2 = ldc(&g_cfin[2][b][w]);
  }
  gbar(w, ++bar);

  // ---------------- decoder steps ----------------
  for (int st = 0; st < NSTEP; ++st){
    const int slot = st & 1, nxt = slot ^ 1;

    // ---- stage A: argmax-reduce, embed, attention, z0 (WGs 0..63) ----
    if (w < 64){
      const int bA = w;
      int tok = 0;                                  // SOS
      if (st > 0){
        float v = -1e38f; int idx = 0;
        if (tid < 256){ v = ldc(&g_wmax[tid][bA]); idx = ldi(&g_wmaxi[tid][bA]); }
        #pragma unroll
        for (int m = 1; m < 64; m <<= 1){
          float ov = __shfl_xor(v, m); int oi = __shfl_xor(idx, m);
          if (ov > v || (ov == v && oi < idx)){ v = ov; idx = oi; }
        }
        if ((tid & 63) == 0){ s_rv[tid >> 6] = v; s_ri[tid >> 6] = idx; }
        __syncthreads();
        if (tid == 0){
          float bv2 = s_rv[0]; int bi2 = s_ri[0];
          for (int q2 = 1; q2 < 8; ++q2){
            float ov = s_rv[q2]; int oi = s_ri[q2];
            if (ov > bv2 || (ov == bv2 && oi < bi2)){ bv2 = ov; bi2 = oi; }
          }
          s_ri[0] = bi2;
        }
        __syncthreads();
        tok = s_ri[0];
      }
      if (tid < 256)
        s_hs[tid] = ldc(&g_hdec[slot][0][bA][tid]) + ldc(&g_hdec[slot][1][bA][tid])
                  + ldc(&g_hdec[slot][2][bA][tid]);
      __syncthreads();
      if (tid < 256){                                // q = hsum @ Wq.T + bq
        float a = p_bq[tid];
        const float4* wr = (const float4*)(p_Wq + (size_t)tid*HH);
        #pragma unroll 8
        for (int k4 = 0; k4 < 64; ++k4){
          float4 wv = wr[k4]; float4 h4 = *(const float4*)&s_hs[k4*4]; DOT4(a, h4, wv);
        }
        s_q[tid] = a;
      }
      __syncthreads();
      if (tid < 256){                                // scores (kp cached, reused 25x)
        float a = 0.f;
        const float4* kr = (const float4*)&g_kp[bA][tid][0];
        #pragma unroll 8
        for (int k4 = 0; k4 < 64; ++k4){
          float4 kv = kr[k4]; float4 q4 = *(const float4*)&s_q[k4*4]; DOT4(a, q4, kv);
        }
        s_sc[tid] = a * 0.0625f;                     // 1/sqrt(256)
      }
      __syncthreads();
      {                                              // softmax
        float sv = (tid < 256) ? s_sc[tid] : -1e38f;
        float m2 = sv;
        #pragma unroll
        for (int m = 1; m < 64; m <<= 1) m2 = fmaxf(m2, __shfl_xor(m2, m));
        if ((tid & 63) == 0) s_rv[tid >> 6] = m2;
        __syncthreads();
        if (tid == 0){ float mm = s_rv[0]; for (int q2 = 1; q2 < 8; ++q2) mm = fmaxf(mm, s_rv[q2]); s_rv[0] = mm; }
        __syncthreads();
        const float mx = s_rv[0];
        float ev = (tid < 256) ? expf(sv - mx) : 0.f;
        float ss = ev;
        #pragma unroll
        for (int m = 1; m < 64; m <<= 1) ss += __shfl_xor(ss, m);
        __syncthreads();
        if ((tid & 63) == 0) s_rv[tid >> 6] = ss;
        __syncthreads();
        if (tid == 0){ float t2 = 0.f; for (int q2 = 0; q2 < 8; ++q2) t2 += s_rv[q2]; s_rv[0] = t2; }
        __syncthreads();
        if (tid < 256) s_at[tid] = ev / s_rv[0];
      }
      __syncthreads();
      if (tid < 256){                                // ctx = attn @ vp (cached)
        float a = 0.f;
        const float* vb = &g_vp[bA][0][tid];
        #pragma unroll 4
        for (int t4 = 0; t4 < 64; ++t4){
          float4 a4 = *(const float4*)&s_at[t4*4];
          a += a4.x*vb[(size_t)(t4*4+0)*HH] + a4.y*vb[(size_t)(t4*4+1)*HH]
             + a4.z*vb[(size_t)(t4*4+2)*HH] + a4.w*vb[(size_t)(t4*4+3)*HH];
        }
        s_ctx[tid] = a;
      }
      __syncthreads();
      if (tid < 256){                                // ctx @ Wo.T + bo ; z0
        float a = p_bo[tid];
        const float4* wr = (const float4*)(p_Wo + (size_t)tid*HH);
        #pragma unroll 8
        for (int k4 = 0; k4 < 64; ++k4){
          float4 wv = wr[k4]; float4 c4 = *(const float4*)&s_ctx[k4*4]; DOT4(a, c4, wv);
        }
        stc(&g_z0[bA][256 + tid], a);
        stc(&g_z0[bA][tid], p_demb[(size_t)tok*HH + tid]);
      }
    }
    gbar(w, ++bar);

    // ---- stages B/C/D: 3 LSTM layers, h=w per WG ----
    {
      float g4[4];
      dec_gates<3, 0>(s_w, &g_z0[b][0], &g_z0[b][256], &g_hdec[slot][0][b][0], j, g4);
      if (j == 0){
        float iv = g4[0]+s_bdec[0], fv = g4[1]+s_bdec[1], gv = g4[2]+s_bdec[2], ov = g4[3]+s_bdec[3];
        float c2 = sigf(fv)*c_d0 + sigf(iv)*tanhf(gv); c_d0 = c2;
        stc(&g_hdec[nxt][0][b][w], sigf(ov)*tanhf(c2));
      }
    }
    gbar(w, ++bar);
    {
      float g4[4];
      dec_gates<2, 3456>(s_w, &g_hdec[nxt][0][b][0], &g_hdec[slot][1][b][0], nullptr, j, g4);
      if (j == 0){
        float iv = g4[0]+s_bdec[4], fv = g4[1]+s_bdec[5], gv = g4[2]+s_bdec[6], ov = g4[3]+s_bdec[7];
        float c2 = sigf(fv)*c_d1 + sigf(iv)*tanhf(gv); c_d1 = c2;
        stc(&g_hdec[nxt][1][b][w], sigf(ov)*tanhf(c2));
      }
    }
    gbar(w, ++bar);
    {
      float g4[4];
      dec_gates<2, 5760>(s_w, &g_hdec[nxt][1][b][0], &g_hdec[slot][2][b][0], nullptr, j, g4);
      if (j == 0){
        float iv = g4[0]+s_bdec[8], fv = g4[1]+s_bdec[9], gv = g4[2]+s_bdec[10], ov = g4[3]+s_bdec[11];
        float c2 = sigf(fv)*c_d2 + sigf(iv)*tanhf(gv); c_d2 = c2;
        stc(&g_hdec[nxt][2][b][w], sigf(ov)*tanhf(c2));
      }
    }
    gbar(w, ++bar);

    // ---- stage E: logits GEMM, 2 classes x 8 batches per thread, wave-local argmax ----
    {
      {  // coalesced coherent staging of h2 (64x256) into LDS
        const float* src = &g_hdec[nxt][2][0][0];
        #pragma unroll
        for (int u = 0; u < 16; ++u){
          int fo = 2*(tid + 512*u);
          float2 v = ld2(src + fo);
          *(float2*)(s_h2 + fo) = v;
        }
      }
      __syncthreads();

      const int cs = tid & 63, qb = tid >> 6;        // qb = wave id; batches qb*8..qb*8+7
      const bool ok0 = (2*cs)   < 125;
      const bool ok1 = (2*cs+1) < 125;
      const int c0 = w*125 + 2*cs, c1 = c0 + 1;
      const float4* wr0 = (const float4*)(p_dW + (size_t)(ok0 ? c0 : w*125)*HH);
      const float4* wr1 = (const float4*)(p_dW + (size_t)(ok1 ? c1 : w*125)*HH);
      const float4* zr[8];
      #pragma unroll
      for (int r = 0; r < 8; ++r) zr[r] = (const float4*)&s_h2[(qb*8 + r)*HH];
      float a0[8], a1[8];
      #pragma unroll
      for (int r = 0; r < 8; ++r){ a0[r] = 0.f; a1[r] = 0.f; }
      for (int k4 = 0; k4 < 64; ++k4){
        float4 w0 = wr0[k4], w1 = wr1[k4];
        #pragma unroll
        for (int r = 0; r < 8; ++r){
          float4 z4 = zr[r][k4];
          DOT4(a0[r], z4, w0);
          DOT4(a1[r], z4, w1);
        }
      }
      const float bias0 = ok0 ? p_db[c0] : 0.f;
      const float bias1 = ok1 ? p_db[c1] : 0.f;
      #pragma unroll
      for (int r = 0; r < 8; ++r){
        const int bb = qb*8 + r;
        float val0 = a0[r] + bias0, val1 = a1[r] + bias1;
        float* orow = p_out + ((size_t)bb*NSTEP + st)*NCLS;
        if (ok0) orow[c0] = val0;
        if (ok1) orow[c1] = val1;
        float v = ok0 ? val0 : -1e38f;
        int idx  = ok0 ? c0 : 0x7fffffff;
        if (ok1 && val1 > v){ v = val1; idx = c1; }   // tie keeps c0 (lower index)
        #pragma unroll
        for (int m = 1; m < 64; m <<= 1){
          float ov = __shfl_xor(v, m); int oi = __shfl_xor(idx, m);
          if (ov > v || (ov == v && oi < idx)){ v = ov; idx = oi; }  // first-index tie-break
        }
        if (cs == 0){ stc(&g_wmax[w][bb], v); sti(&g_wmaxi[w][bb], idx); }
      }
    }
    gbar(w, ++bar);
  }
}

extern "C" void kernel_launch(void* const* d_in, const int* in_sizes, int n_in,
                              void* d_out, int out_size, void* d_ws, size_t ws_size,
                              hipStream_t stream){
  (void)in_sizes; (void)n_in; (void)out_size; (void)d_ws; (void)ws_size;
  const int*   x     = (const int*)d_in[0];
  const float* eemb  = (const float*)d_in[2];
  const float* eWih  = (const float*)d_in[3];
  const float* eWhh  = (const float*)d_in[4];
  const float* ebih  = (const float*)d_in[5];
  const float* ebhh  = (const float*)d_in[6];
  const float* Wq    = (const float*)d_in[7];
  const float* bq    = (const float*)d_in[8];
  const float* Wk    = (const float*)d_in[9];
  const float* bk    = (const float*)d_in[10];
  const float* Wv    = (const float*)d_in[11];
  const float* bv    = (const float*)d_in[12];
  const float* Wo    = (const float*)d_in[13];
  const float* bo    = (const float*)d_in[14];
  const float* demb  = (const float*)d_in[15];
  const float* dWih0 = (const float*)d_in[16];
  const float* dWihR = (const float*)d_in[17];
  const float* dWhh  = (const float*)d_in[18];
  const float* dbih  = (const float*)d_in[19];
  const float* dbhh  = (const float*)d_in[20];
  const float* dW    = (const float*)d_in[21];
  const float* db    = (const float*)d_in[22];
  float* out = (float*)d_out;

  k_zero_flags<<<dim3(1), dim3(256), 0, stream>>>();
  k_main<<<dim3(256), dim3(512), 0, stream>>>(
      x, eemb, eWih, eWhh, ebih, ebhh,
      Wq, bq, Wk, bk, Wv, bv, Wo, bo,
      demb, dWih0, dWihR, dWhh, dbih, dbhh, dW, db, out);
}

// Round 8
// 5717.071 us; speedup vs baseline: 1.3506x; 1.0256x over previous
//
#include <hip/hip_runtime.h>
#include <math.h>

// EncoderDecoderAttentionModel: B=64, T=256, H=D=256, L=3, NSTEPS=25, C=32000
#define TT    256
#define NB    64
#define HH    256
#define NSTEP 25
#define NCLS  32000
#define PADI  3
#define RING  4

// ---------------- static device scratch ----------------
__device__ __align__(16) float g_hring[3][RING][NB][HH]; // encoder h ring (sc1)
__device__ __align__(16) float g_enchid[TT][NB][HH];     // plain (cross-kernel)
__device__ __align__(16) float g_kp[NB][TT][HH];
__device__ __align__(16) float g_vp[NB][TT][HH];
__device__ __align__(16) float g_cfin[3][NB][HH];        // plain (cross-kernel)
__device__ __align__(16) float g_hdec[2][3][NB][HH];     // decoder h ping-pong (sc1)
__device__ __align__(16) float g_z0[NB][512];            // (sc1)
__device__ float    g_wmax[256][NB];
__device__ int      g_wmaxi[256][NB];
__device__ int      g_len[NB];
__device__ unsigned g_arrive[256];                       // k_dec global barrier
__device__ unsigned g_rel[256];                          // 16 fan-out lines
__device__ unsigned g_earr[3][64];                       // k_enc per-layer arrive
__device__ unsigned g_erel[3][64];                       // 4 fan-out copies at [l][16i]

__device__ __forceinline__ float sigf(float v){ return 1.0f / (1.0f + expf(-v)); }

#define SCOPE_AG __HIP_MEMORY_SCOPE_AGENT
typedef unsigned long long u64;
__device__ __forceinline__ float2 ld2(const float* p){
  u64 v = __hip_atomic_load((const u64*)p, __ATOMIC_RELAXED, SCOPE_AG);
  float2 r; __builtin_memcpy(&r, &v, 8); return r;
}
__device__ __forceinline__ float ldc(const float* p){ return __hip_atomic_load(p, __ATOMIC_RELAXED, SCOPE_AG); }
__device__ __forceinline__ void  stc(float* p, float v){ __hip_atomic_store(p, v, __ATOMIC_RELAXED, SCOPE_AG); }
__device__ __forceinline__ int   ldi(const int* p){ return __hip_atomic_load(p, __ATOMIC_RELAXED, SCOPE_AG); }
__device__ __forceinline__ void  sti(int* p, int v){ __hip_atomic_store(p, v, __ATOMIC_RELAXED, SCOPE_AG); }
__device__ __forceinline__ unsigned ldu(const unsigned* p){ return __hip_atomic_load(p, __ATOMIC_RELAXED, SCOPE_AG); }
__device__ __forceinline__ void  stu(unsigned* p, unsigned v){ __hip_atomic_store(p, v, __ATOMIC_RELAXED, SCOPE_AG); }

#define DOT4(a_, x_, w_) (a_) += (x_).x*(w_).x + (x_).y*(w_).y + (x_).z*(w_).z + (x_).w*(w_).w

// ---------------- k_init: zero barriers + ring seed + lengths ----------------
__global__ void __launch_bounds__(256) k_init(const int* __restrict__ p_x){
  const int blk = blockIdx.x, tid = threadIdx.x;
  if (blk < 192){
    int idx = blk*256 + tid;                 // 49152 = 3*64*256 (slot RING-1)
    int l = idx >> 14, rem = idx & 16383;
    g_hring[l][RING-1][rem >> 8][rem & 255] = 0.f;
  } else {
    __shared__ int s_c[4];
    int b = blk - 192;
    int cnt = (p_x[b*TT + tid] != PADI) ? 1 : 0;
    #pragma unroll
    for (int m = 1; m < 64; m <<= 1) cnt += __shfl_xor(cnt, m);
    if ((tid & 63) == 0) s_c[tid >> 6] = cnt;
    __syncthreads();
    if (tid == 0) g_len[b] = s_c[0] + s_c[1] + s_c[2] + s_c[3];
  }
  if (blk == 0){ g_arrive[tid] = 0u; g_rel[tid] = 0u; }
  if (blk == 1 && tid < 192){
    ((unsigned*)g_earr)[tid] = 0u;
    ((unsigned*)g_erel)[tid] = 0u;
  }
}

// ---------------- k_enc: 3-layer pipelined encoder, 64-WG layer barriers ----------------
__global__ void __launch_bounds__(512, 1)
k_enc(const int*   __restrict__ p_x,
      const float* __restrict__ p_eemb,
      const float* __restrict__ p_eWih, const float* __restrict__ p_eWhh,
      const float* __restrict__ p_ebih, const float* __restrict__ p_ebhh)
{
  __shared__ __align__(16) float s_W[8192];   // [16 rows][512] identity layout
  __shared__ float s_gat[1024];               // [16 rows][64 b]
  __shared__ float s_b[16];
  __shared__ int   s_len[64];

  const int w = blockIdx.x, tid = threadIdx.x;
  const int l = w >> 6, q = w & 63;           // layer, h-group (owns h 4q..4q+3)
  const int b2 = tid >> 4, j = tid & 15;      // 2 batches/thread, 16-way K-split
  const int ce = tid >> 6, cb = tid & 63;     // cell-update mapping (tid<256)

  for (int fi = tid; fi < 8192; fi += 512){
    int row = fi >> 9, k = fi & 511;
    int e = row >> 2, g = row & 3;
    int wrow = g*256 + 4*q + e;
    s_W[fi] = (k < 256) ? p_eWih[((size_t)l*1024 + wrow)*256 + k]
                        : p_eWhh[((size_t)l*1024 + wrow)*256 + (k - 256)];
  }
  if (tid < 16){
    int e = tid >> 2, g = tid & 3;
    int wrow = g*256 + 4*q + e;
    s_b[tid] = p_ebih[l*1024 + wrow] + p_ebhh[l*1024 + wrow];
  }
  if (tid < 64) s_len[tid] = g_len[tid];
  float c_reg = 0.f, h_frz = 0.f;
  __syncthreads();

  for (int t = 0; t < TT; ++t){
    // waits: own rel>=t, upstream rel>=t+1, downstream backpressure rel>=t-3
    if (tid == 0){
      const int li = (q & 3) << 4;
      for (;;){
        bool ok = (ldu(&g_erel[l][li]) >= (unsigned)t);
        if (ok && l > 0)          ok = (ldu(&g_erel[l-1][li]) >= (unsigned)(t+1));
        if (ok && l < 2 && t >= 4) ok = (ldu(&g_erel[l+1][li]) >= (unsigned)(t-3));
        if (ok) break;
        __builtin_amdgcn_s_sleep(1);
      }
    }
    __syncthreads();

    // inputs: x-slice (embed or below-layer h) + own-layer h[t-1]
    float4 xin[2][4], hin[2][4];
    #pragma unroll
    for (int bb = 0; bb < 2; ++bb){
      const int batch = 2*b2 + bb;
      if (l == 0){
        const float* xs = p_eemb + (size_t)p_x[batch*TT + t]*HH;
        #pragma unroll
        for (int u = 0; u < 4; ++u) xin[bb][u] = *(const float4*)(xs + u*64 + 4*j);
      } else {
        const float* xs = &g_hring[l-1][t & (RING-1)][batch][0];
        #pragma unroll
        for (int u = 0; u < 4; ++u){
          float2 a = ld2(xs + u*64 + 4*j), c = ld2(xs + u*64 + 4*j + 2);
          xin[bb][u] = make_float4(a.x, a.y, c.x, c.y);
        }
      }
      const float* hs = &g_hring[l][(t + RING - 1) & (RING-1)][batch][0];
      #pragma unroll
      for (int u = 0; u < 4; ++u){
        float2 a = ld2(hs + u*64 + 4*j), c = ld2(hs + u*64 + 4*j + 2);
        hin[bb][u] = make_float4(a.x, a.y, c.x, c.y);
      }
    }

    float acc[16][2];
    #pragma unroll
    for (int r = 0; r < 16; ++r){ acc[r][0] = 0.f; acc[r][1] = 0.f; }
    #pragma unroll
    for (int u = 0; u < 8; ++u){
      float4 i0 = (u < 4) ? xin[0][u] : hin[0][u-4];
      float4 i1 = (u < 4) ? xin[1][u] : hin[1][u-4];
      #pragma unroll
      for (int row = 0; row < 16; ++row){
        float4 wv = *(const float4*)&s_W[row*512 + u*64 + 4*j];
        DOT4(acc[row][0], i0, wv);
        DOT4(acc[row][1], i1, wv);
      }
    }
    #pragma unroll
    for (int row = 0; row < 16; ++row){
      #pragma unroll
      for (int bb = 0; bb < 2; ++bb){
        float v = acc[row][bb];
        v += __shfl_xor(v, 1); v += __shfl_xor(v, 2);
        v += __shfl_xor(v, 4); v += __shfl_xor(v, 8);
        acc[row][bb] = v;
      }
    }
    if (j == 0){
      #pragma unroll
      for (int row = 0; row < 16; ++row){
        s_gat[row*64 + 2*b2    ] = acc[row][0];
        s_gat[row*64 + 2*b2 + 1] = acc[row][1];
      }
    }
    __syncthreads();

    if (tid < 256){
      float iv = s_gat[(ce*4+0)*64 + cb] + s_b[ce*4+0];
      float fv = s_gat[(ce*4+1)*64 + cb] + s_b[ce*4+1];
      float gv = s_gat[(ce*4+2)*64 + cb] + s_b[ce*4+2];
      float ov = s_gat[(ce*4+3)*64 + cb] + s_b[ce*4+3];
      float c2 = sigf(fv)*c_reg + sigf(iv)*tanhf(gv);
      float h2 = sigf(ov)*tanhf(c2);
      bool valid = (t < s_len[cb]);
      if (valid) c_reg = c2;
      h_frz = valid ? h2 : h_frz;
      stc(&g_hring[l][t & (RING-1)][cb][4*q + ce], h_frz);
      if (l == 2) g_enchid[t][cb][4*q + ce] = valid ? h_frz : 0.f;  // plain
    }

    asm volatile("s_waitcnt vmcnt(0)" ::: "memory");
    __syncthreads();
    if (tid == 0) stu(&g_earr[l][q], (unsigned)(t+1));
    if (q == 0 && tid < 64){
      while (!__all(ldu(&g_earr[l][tid]) >= (unsigned)(t+1)))
        __builtin_amdgcn_s_sleep(1);
      if (tid < 4) stu(&g_erel[l][tid << 4], (unsigned)(t+1));
    }
    __syncthreads();
  }

  if (tid < 256) g_cfin[l][cb][4*q + ce] = c_reg;   // plain; kernel-end flush
}

// ---------------- k_dec: KV + 25-step decoder (R7 structure) ----------------
__device__ __forceinline__ void gbar(int w, unsigned target){
  asm volatile("s_waitcnt vmcnt(0)" ::: "memory");
  __syncthreads();
  if (threadIdx.x == 0) stu(&g_arrive[w], target);
  if (w == 0){
    if (threadIdx.x < 64){
      const int i4 = threadIdx.x * 4;
      for (;;){
        unsigned a0 = ldu(&g_arrive[i4+0]);
        unsigned a1 = ldu(&g_arrive[i4+1]);
        unsigned a2 = ldu(&g_arrive[i4+2]);
        unsigned a3 = ldu(&g_arrive[i4+3]);
        if (__all((a0>=target) && (a1>=target) && (a2>=target) && (a3>=target))) break;
        __builtin_amdgcn_s_sleep(1);
      }
      if (threadIdx.x < 16) stu(&g_rel[threadIdx.x << 4], target);
    }
  } else {
    if (threadIdx.x == 0){
      const unsigned* line = &g_rel[(w >> 4) << 4];
      while (ldu(line) < target) __builtin_amdgcn_s_sleep(1);
    }
  }
  __syncthreads();
}

template<int NCB, int BASE>
__device__ __forceinline__ void dec_gates(const float* sw, const float* i0, const float* i1,
                                          const float* i2, int j, float out4[4]){
  float a0=0.f, a1=0.f, a2=0.f, a3=0.f;
  const float* ips[3] = { i0, i1, i2 };
  #pragma unroll
  for (int cb = 0; cb < NCB; ++cb){
    float2 xin[16];
    #pragma unroll
    for (int u = 0; u < 16; ++u) xin[u] = ld2(ips[cb] + u*16 + 2*j);
    #pragma unroll
    for (int u2 = 0; u2 < 8; ++u2){
      float2 pa = xin[2*u2], pb = xin[2*u2+1];
      const float* wb = &sw[BASE + (((cb*4+0)*8+j)*36) + u2*4];
      float4 w0 = *(const float4*)(wb);
      float4 w1 = *(const float4*)(wb + 288);
      float4 w2 = *(const float4*)(wb + 576);
      float4 w3 = *(const float4*)(wb + 864);
      a0 += pa.x*w0.x + pa.y*w0.y + pb.x*w0.z + pb.y*w0.w;
      a1 += pa.x*w1.x + pa.y*w1.y + pb.x*w1.z + pb.y*w1.w;
      a2 += pa.x*w2.x + pa.y*w2.y + pb.x*w2.z + pb.y*w2.w;
      a3 += pa.x*w3.x + pa.y*w3.y + pb.x*w3.z + pb.y*w3.w;
    }
  }
  #pragma unroll
  for (int m = 1; m < 8; m <<= 1){
    a0 += __shfl_xor(a0, m); a1 += __shfl_xor(a1, m);
    a2 += __shfl_xor(a2, m); a3 += __shfl_xor(a3, m);
  }
  out4[0]=a0; out4[1]=a1; out4[2]=a2; out4[3]=a3;
}

__global__ void __launch_bounds__(512, 1)
k_dec(const float* __restrict__ p_Wq, const float* __restrict__ p_bq,
      const float* __restrict__ p_Wk, const float* __restrict__ p_bk,
      const float* __restrict__ p_Wv, const float* __restrict__ p_bv,
      const float* __restrict__ p_Wo, const float* __restrict__ p_bo,
      const float* __restrict__ p_demb,
      const float* __restrict__ p_dWih0, const float* __restrict__ p_dWihR,
      const float* __restrict__ p_dWhh,
      const float* __restrict__ p_dbih,  const float* __restrict__ p_dbhh,
      const float* __restrict__ p_dW,    const float* __restrict__ p_db,
      float* __restrict__ p_out)
{
  __shared__ __align__(16) float s_w[8064];
  __shared__ __align__(16) float s_h2[NB*HH];
  __shared__ float s_bdec[12];
  __shared__ __align__(16) float s_hs[256];
  __shared__ __align__(16) float s_q[256];
  __shared__ __align__(16) float s_sc[256];
  __shared__ __align__(16) float s_at[256];
  __shared__ __align__(16) float s_ctx[256];
  __shared__ float s_rv[8];  __shared__ int s_ri[8];

  const int w   = blockIdx.x;
  const int tid = threadIdx.x;
  const int b   = tid >> 3;
  const int j   = tid & 7;
  unsigned bar  = 0;

  // ---- K/V projections (enchid plain-read, cross-kernel coherent) ----
  {
    const int b3 = w >> 2, t0 = (w & 3) * 64;
    const int n1 = tid & 127, rq = tid >> 7;
    for (int p = 0; p < 4; ++p){
      const int n = p*128 + n1;
      const float* wrow = (n < 256) ? (p_Wk + (size_t)n*HH) : (p_Wv + (size_t)(n-256)*HH);
      const float bias  = (n < 256) ? p_bk[n] : p_bv[n-256];
      const float4* wr4 = (const float4*)wrow;
      const float* hb = &g_enchid[t0 + rq*16][b3][0];
      const float4* hr[16];
      #pragma unroll
      for (int r = 0; r < 16; ++r) hr[r] = (const float4*)(hb + (size_t)r*NB*HH);
      float a16[16];
      #pragma unroll
      for (int r = 0; r < 16; ++r) a16[r] = 0.f;
      for (int k4 = 0; k4 < 64; ++k4){
        float4 wv = wr4[k4];
        #pragma unroll
        for (int r = 0; r < 16; ++r){ float4 h4 = hr[r][k4]; DOT4(a16[r], h4, wv); }
      }
      float* orow = (n < 256) ? &g_kp[b3][t0 + rq*16][n] : &g_vp[b3][t0 + rq*16][n-256];
      #pragma unroll
      for (int r = 0; r < 16; ++r) stc(orow + (size_t)r*HH, a16[r] + bias);
    }
  }

  // ---- decoder weights for h=w -> LDS (K-permuted stride-36) ----
  for (int fi = tid; fi < 3072; fi += 512){
    int g = fi / 768, k = fi % 768; int row = g*256 + w;
    float v = (k < 512) ? p_dWih0[(size_t)row*512 + k]
                        : p_dWhh[(size_t)row*HH + (k - 512)];
    int cb = k >> 8, kk = k & 255;
    s_w[(((cb*4 + g)*8 + ((kk & 15) >> 1))*36) + (((kk >> 4) << 1) | (kk & 1))] = v;
  }
  for (int fi = tid; fi < 2048; fi += 512){
    int g = fi / 512, k = fi % 512; int row = g*256 + w;
    float v = (k < 256) ? p_dWihR[(size_t)row*HH + k]
                        : p_dWhh[(size_t)(1024 + row)*HH + (k - 256)];
    int cb = k >> 8, kk = k & 255;
    s_w[3456 + (((cb*4 + g)*8 + ((kk & 15) >> 1))*36) + (((kk >> 4) << 1) | (kk & 1))] = v;
  }
  for (int fi = tid; fi < 2048; fi += 512){
    int g = fi / 512, k = fi % 512; int row = g*256 + w;
    float v = (k < 256) ? p_dWihR[(size_t)(1024 + row)*HH + k]
                        : p_dWhh[(size_t)(2048 + row)*HH + (k - 256)];
    int cb = k >> 8, kk = k & 255;
    s_w[5760 + (((cb*4 + g)*8 + ((kk & 15) >> 1))*36) + (((kk >> 4) << 1) | (kk & 1))] = v;
  }
  if (tid < 12){
    int l = tid >> 2, g = tid & 3; int row = g*256 + w;
    s_bdec[tid] = p_dbih[l*1024 + row] + p_dbhh[l*1024 + row];
  }
  gbar(w, ++bar);

  // ---- decoder init: h from ring slot RING-1 (t=255), c from cfin ----
  if (tid < 192){
    int fi = w*192 + tid;
    int l = fi >> 14, rem = fi & 16383;
    stc(&g_hdec[0][l][rem >> 8][rem & 255], ldc(&g_hring[l][RING-1][rem >> 8][rem & 255]));
  }
  float c_d0 = 0.f, c_d1 = 0.f, c_d2 = 0.f;
  if (j == 0){
    c_d0 = g_cfin[0][b][w]; c_d1 = g_cfin[1][b][w]; c_d2 = g_cfin[2][b][w];
  }
  gbar(w, ++bar);

  for (int st = 0; st < NSTEP; ++st){
    const int slot = st & 1, nxt = slot ^ 1;

    // ---- stage A: argmax-reduce, embed, attention, z0 (WGs 0..63) ----
    if (w < 64){
      const int bA = w;
      int tok = 0;
      if (st > 0){
        float v = -1e38f; int idx = 0;
        if (tid < 256){ v = ldc(&g_wmax[tid][bA]); idx = ldi(&g_wmaxi[tid][bA]); }
        #pragma unroll
        for (int m = 1; m < 64; m <<= 1){
          float ov = __shfl_xor(v, m); int oi = __shfl_xor(idx, m);
          if (ov > v || (ov == v && oi < idx)){ v = ov; idx = oi; }
        }
        if ((tid & 63) == 0){ s_rv[tid >> 6] = v; s_ri[tid >> 6] = idx; }
        __syncthreads();
        if (tid == 0){
          float bv2 = s_rv[0]; int bi2 = s_ri[0];
          for (int q2 = 1; q2 < 8; ++q2){
            float ov = s_rv[q2]; int oi = s_ri[q2];
            if (ov > bv2 || (ov == bv2 && oi < bi2)){ bv2 = ov; bi2 = oi; }
          }
          s_ri[0] = bi2;
        }
        __syncthreads();
        tok = s_ri[0];
      }
      if (tid < 256)
        s_hs[tid] = ldc(&g_hdec[slot][0][bA][tid]) + ldc(&g_hdec[slot][1][bA][tid])
                  + ldc(&g_hdec[slot][2][bA][tid]);
      __syncthreads();
      if (tid < 256){
        float a = p_bq[tid];
        const float4* wr = (const float4*)(p_Wq + (size_t)tid*HH);
        #pragma unroll 8
        for (int k4 = 0; k4 < 64; ++k4){
          float4 wv = wr[k4]; float4 h4 = *(const float4*)&s_hs[k4*4]; DOT4(a, h4, wv);
        }
        s_q[tid] = a;
      }
      __syncthreads();
      if (tid < 256){
        float a = 0.f;
        const float4* kr = (const float4*)&g_kp[bA][tid][0];
        #pragma unroll 8
        for (int k4 = 0; k4 < 64; ++k4){
          float4 kv = kr[k4]; float4 q4 = *(const float4*)&s_q[k4*4]; DOT4(a, q4, kv);
        }
        s_sc[tid] = a * 0.0625f;
      }
      __syncthreads();
      {
        float sv = (tid < 256) ? s_sc[tid] : -1e38f;
        float m2 = sv;
        #pragma unroll
        for (int m = 1; m < 64; m <<= 1) m2 = fmaxf(m2, __shfl_xor(m2, m));
        if ((tid & 63) == 0) s_rv[tid >> 6] = m2;
        __syncthreads();
        if (tid == 0){ float mm = s_rv[0]; for (int q2 = 1; q2 < 8; ++q2) mm = fmaxf(mm, s_rv[q2]); s_rv[0] = mm; }
        __syncthreads();
        const float mx = s_rv[0];
        float ev = (tid < 256) ? expf(sv - mx) : 0.f;
        float ss = ev;
        #pragma unroll
        for (int m = 1; m < 64; m <<= 1) ss += __shfl_xor(ss, m);
        __syncthreads();
        if ((tid & 63) == 0) s_rv[tid >> 6] = ss;
        __syncthreads();
        if (tid == 0){ float t2 = 0.f; for (int q2 = 0; q2 < 8; ++q2) t2 += s_rv[q2]; s_rv[0] = t2; }
        __syncthreads();
        if (tid < 256) s_at[tid] = ev / s_rv[0];
      }
      __syncthreads();
      if (tid < 256){
        float a = 0.f;
        const float* vb = &g_vp[bA][0][tid];
        #pragma unroll 4
        for (int t4 = 0; t4 < 64; ++t4){
          float4 a4 = *(const float4*)&s_at[t4*4];
          a += a4.x*vb[(size_t)(t4*4+0)*HH] + a4.y*vb[(size_t)(t4*4+1)*HH]
             + a4.z*vb[(size_t)(t4*4+2)*HH] + a4.w*vb[(size_t)(t4*4+3)*HH];
        }
        s_ctx[tid] = a;
      }
      __syncthreads();
      if (tid < 256){
        float a = p_bo[tid];
        const float4* wr = (const float4*)(p_Wo + (size_t)tid*HH);
        #pragma unroll 8
        for (int k4 = 0; k4 < 64; ++k4){
          float4 wv = wr[k4]; float4 c4 = *(const float4*)&s_ctx[k4*4]; DOT4(a, c4, wv);
        }
        stc(&g_z0[bA][256 + tid], a);
        stc(&g_z0[bA][tid], p_demb[(size_t)tok*HH + tid]);
      }
    }
    gbar(w, ++bar);

    // ---- stages B/C/D: 3 LSTM layers, h=w per WG ----
    {
      float g4[4];
      dec_gates<3, 0>(s_w, &g_z0[b][0], &g_z0[b][256], &g_hdec[slot][0][b][0], j, g4);
      if (j == 0){
        float iv = g4[0]+s_bdec[0], fv = g4[1]+s_bdec[1], gv = g4[2]+s_bdec[2], ov = g4[3]+s_bdec[3];
        float c2 = sigf(fv)*c_d0 + sigf(iv)*tanhf(gv); c_d0 = c2;
        stc(&g_hdec[nxt][0][b][w], sigf(ov)*tanhf(c2));
      }
    }
    gbar(w, ++bar);
    {
      float g4[4];
      dec_gates<2, 3456>(s_w, &g_hdec[nxt][0][b][0], &g_hdec[slot][1][b][0], nullptr, j, g4);
      if (j == 0){
        float iv = g4[0]+s_bdec[4], fv = g4[1]+s_bdec[5], gv = g4[2]+s_bdec[6], ov = g4[3]+s_bdec[7];
        float c2 = sigf(fv)*c_d1 + sigf(iv)*tanhf(gv); c_d1 = c2;
        stc(&g_hdec[nxt][1][b][w], sigf(ov)*tanhf(c2));
      }
    }
    gbar(w, ++bar);
    {
      float g4[4];
      dec_gates<2, 5760>(s_w, &g_hdec[nxt][1][b][0], &g_hdec[slot][2][b][0], nullptr, j, g4);
      if (j == 0){
        float iv = g4[0]+s_bdec[8], fv = g4[1]+s_bdec[9], gv = g4[2]+s_bdec[10], ov = g4[3]+s_bdec[11];
        float c2 = sigf(fv)*c_d2 + sigf(iv)*tanhf(gv); c_d2 = c2;
        stc(&g_hdec[nxt][2][b][w], sigf(ov)*tanhf(c2));
      }
    }
    gbar(w, ++bar);

    // ---- stage E: logits GEMM, 2 classes x 8 batches/thread, wave-local argmax ----
    {
      {
        const float* src = &g_hdec[nxt][2][0][0];
        #pragma unroll
        for (int u = 0; u < 16; ++u){
          int fo = 2*(tid + 512*u);
          float2 v = ld2(src + fo);
          *(float2*)(s_h2 + fo) = v;
        }
      }
      __syncthreads();

      const int cs = tid & 63, qb = tid >> 6;
      const bool ok0 = (2*cs)   < 125;
      const bool ok1 = (2*cs+1) < 125;
      const int c0 = w*125 + 2*cs, c1 = c0 + 1;
      const float4* wr0 = (const float4*)(p_dW + (size_t)(ok0 ? c0 : w*125)*HH);
      const float4* wr1 = (const float4*)(p_dW + (size_t)(ok1 ? c1 : w*125)*HH);
      const float4* zr[8];
      #pragma unroll
      for (int r = 0; r < 8; ++r) zr[r] = (const float4*)&s_h2[(qb*8 + r)*HH];
      float a0[8], a1[8];
      #pragma unroll
      for (int r = 0; r < 8; ++r){ a0[r] = 0.f; a1[r] = 0.f; }
      for (int k4 = 0; k4 < 64; ++k4){
        float4 w0 = wr0[k4], w1 = wr1[k4];
        #pragma unroll
        for (int r = 0; r < 8; ++r){
          float4 z4 = zr[r][k4];
          DOT4(a0[r], z4, w0);
          DOT4(a1[r], z4, w1);
        }
      }
      const float bias0 = ok0 ? p_db[c0] : 0.f;
      const float bias1 = ok1 ? p_db[c1] : 0.f;
      #pragma unroll
      for (int r = 0; r < 8; ++r){
        const int bb = qb*8 + r;
        float val0 = a0[r] + bias0, val1 = a1[r] + bias1;
        float* orow = p_out + ((size_t)bb*NSTEP + st)*NCLS;
        if (ok0) orow[c0] = val0;
        if (ok1) orow[c1] = val1;
        float v = ok0 ? val0 : -1e38f;
        int idx  = ok0 ? c0 : 0x7fffffff;
        if (ok1 && val1 > v){ v = val1; idx = c1; }
        #pragma unroll
        for (int m = 1; m < 64; m <<= 1){
          float ov = __shfl_xor(v, m); int oi = __shfl_xor(idx, m);
          if (ov > v || (ov == v && oi < idx)){ v = ov; idx = oi; }
        }
        if (cs == 0){ stc(&g_wmax[w][bb], v); sti(&g_wmaxi[w][bb], idx); }
      }
    }
    gbar(w, ++bar);
  }
}

extern "C" void kernel_launch(void* const* d_in, const int* in_sizes, int n_in,
                              void* d_out, int out_size, void* d_ws, size_t ws_size,
                              hipStream_t stream){
  (void)in_sizes; (void)n_in; (void)out_size; (void)d_ws; (void)ws_size;
  const int*   x     = (const int*)d_in[0];
  const float* eemb  = (const float*)d_in[2];
  const float* eWih  = (const float*)d_in[3];
  const float* eWhh  = (const float*)d_in[4];
  const float* ebih  = (const float*)d_in[5];
  const float* ebhh  = (const float*)d_in[6];
  const float* Wq    = (const float*)d_in[7];
  const float* bq    = (const float*)d_in[8];
  const float* Wk    = (const float*)d_in[9];
  const float* bk    = (const float*)d_in[10];
  const float* Wv    = (const float*)d_in[11];
  const float* bv    = (const float*)d_in[12];
  const float* Wo    = (const float*)d_in[13];
  const float* bo    = (const float*)d_in[14];
  const float* demb  = (const float*)d_in[15];
  const float* dWih0 = (const float*)d_in[16];
  const float* dWihR = (const float*)d_in[17];
  const float* dWhh  = (const float*)d_in[18];
  const float* dbih  = (const float*)d_in[19];
  const float* dbhh  = (const float*)d_in[20];
  const float* dW    = (const float*)d_in[21];
  const float* db    = (const float*)d_in[22];
  float* out = (float*)d_out;

  k_init<<<dim3(256), dim3(256), 0, stream>>>(x);
  k_enc<<<dim3(192), dim3(512), 0, stream>>>(x, eemb, eWih, eWhh, ebih, ebhh);
  k_dec<<<dim3(256), dim3(512), 0, stream>>>(Wq, bq, Wk, bk, Wv, bv, Wo, bo,
                                             demb, dWih0, dWihR, dWhh, dbih, dbhh,
                                             dW, db, out);
}